// Round 4
// baseline (643.924 us; speedup 1.0000x reference)
//
#include <hip/hip_runtime.h>

typedef __attribute__((ext_vector_type(4))) float f32x4;
typedef __attribute__((ext_vector_type(8))) short s16x8;
typedef __attribute__((ext_vector_type(8))) unsigned short u16x8;

#define AS1 __attribute__((address_space(1)))
#define AS3 __attribute__((address_space(3)))

constexpr int MDIM = 8192;   // batch
constexpr int NDIM = 4096;   // out features
constexpr int KDIM = 4096;   // in features

constexpr int BM = 256, BN = 256, BK = 64;
constexpr int NKT = KDIM / BK;   // 64

__device__ __forceinline__ unsigned short f2bf(float f) {
  unsigned int u = __float_as_uint(f);
  u += 0x7fffu + ((u >> 16) & 1u);   // round-to-nearest-even
  return (unsigned short)(u >> 16);
}

__device__ __forceinline__ void gld_lds16(const unsigned short* g, unsigned short* l) {
  __builtin_amdgcn_global_load_lds((const AS1 void*)g, (AS3 void*)l, 16, 0, 0);
}

// ---- x f32 -> bf16 ----
__global__ void cvt_x_kernel(const float* __restrict__ x, unsigned short* __restrict__ xb) {
  const int n8 = MDIM * KDIM / 8;
  for (int i = blockIdx.x * blockDim.x + threadIdx.x; i < n8; i += gridDim.x * blockDim.x) {
    const float4* p = (const float4*)x + 2 * (size_t)i;
    float4 v0 = p[0], v1 = p[1];
    u16x8 r;
    r[0] = f2bf(v0.x); r[1] = f2bf(v0.y); r[2] = f2bf(v0.z); r[3] = f2bf(v0.w);
    r[4] = f2bf(v1.x); r[5] = f2bf(v1.y); r[6] = f2bf(v1.z); r[7] = f2bf(v1.w);
    *((u16x8*)xb + i) = r;
  }
}

// ---- W[o][k] = params[4095 - o + k], as bf16 [NDIM][KDIM] ----
__global__ void build_w_kernel(const float* __restrict__ params, unsigned short* __restrict__ wb) {
  const int n8 = NDIM * KDIM / 8;
  for (int i = blockIdx.x * blockDim.x + threadIdx.x; i < n8; i += gridDim.x * blockDim.x) {
    int o = i >> 9;
    int k0 = (i & 511) << 3;
    const float* p = params + (NDIM - 1 - o + k0);
    u16x8 r;
#pragma unroll
    for (int e = 0; e < 8; ++e) r[e] = f2bf(p[e]);
    *((u16x8*)wb + i) = r;
  }
}

// ================= 256x256 8-phase bf16 GEMM, fragment read-ahead =================
// C = A * Bw^T + bias ; A[M][K], Bw[N][K] row-major bf16, C f32.
// LDS tile [256][64] bf16, XOR-swizzle col ^= (row&7)<<3 (elements).
// Fragments for phase p+1 are ds_read-issued during phase p (register ping-pong),
// consumed via counted lgkmcnt so the LDS drain hides under MFMA.
__global__ __launch_bounds__(512, 2) void toep_gemm8p(
    const unsigned short* __restrict__ A,
    const unsigned short* __restrict__ Bw,
    const float* __restrict__ bias,
    float* __restrict__ C)
{
  __shared__ unsigned short sA[2][BM * BK];   // 64 KiB
  __shared__ unsigned short sB[2][BN * BK];   // 64 KiB

  constexpr int NBM = MDIM / BM;   // 32
  constexpr int NBN = NDIM / BN;   // 16
  constexpr int NWG = NBM * NBN;   // 512 (divisible by 8)
  int bid = (int)blockIdx.x;
  int swz = (bid & 7) * (NWG >> 3) + (bid >> 3);   // bijective: NWG % 8 == 0
  int bm = swz / NBN, bn = swz % NBN;
  int m0 = bm * BM, n0 = bn * BN;

  int t = (int)threadIdx.x;
  int lane = t & 63, wid = t >> 6;
  int wm = wid >> 2, wn = wid & 3;     // 2 (M) x 4 (N) wave grid; 128x64 per wave
  int lr = lane & 15, lk = lane >> 4;

  // --- staging: dest linear t*16B, source col pre-swizzled ---
  int scol = (((t & 7) ^ ((t >> 3) & 7)) << 3);
  const unsigned short* gA = A + (size_t)(m0 + (t >> 3)) * KDIM + scol;
  const unsigned short* gB = Bw + (size_t)(n0 + (t >> 3)) * KDIM + scol;

#define STG_A(c, kt, R0) gld_lds16(gA + (size_t)(R0) * KDIM + (kt) * 64, &sA[c][(R0) * 64 + t * 8])
#define STG_B(c, kt, R0) gld_lds16(gB + (size_t)(R0) * KDIM + (kt) * 64, &sB[c][(R0) * 64 + t * 8])

  // --- ds_read fragment addressing (swizzled) ---
  int aswz = (lr & 7) << 3;
  int c0 = (lk * 8) ^ aswz;          // ks=0 physical col (elements)
  int c1 = (32 + lk * 8) ^ aswz;     // ks=1

  s16x8 avLO[2][4][2];   // ping-pong: rows wm*128 + 0..63
  s16x8 avHI[4][2];      // rows wm*128 + 64..127 (single-buffered)
  s16x8 bv0[2][2][2];    // ping-pong: nsub 0
  s16x8 bv1[2][2];       // nsub 1 (single-buffered)
  f32x4 acc[8][4];
#pragma unroll
  for (int i = 0; i < 8; ++i)
#pragma unroll
    for (int j = 0; j < 4; ++j) acc[i][j] = (f32x4){0.f, 0.f, 0.f, 0.f};

#define LDALO(c, P) do { \
  _Pragma("unroll") \
  for (int mi = 0; mi < 4; ++mi) { \
    const unsigned short* p_ = &sA[c][(wm * 128 + mi * 16 + lr) * 64]; \
    avLO[P][mi][0] = *(const s16x8*)(p_ + c0); \
    avLO[P][mi][1] = *(const s16x8*)(p_ + c1); \
  } } while (0)

#define LDAHI(c) do { \
  _Pragma("unroll") \
  for (int mi = 0; mi < 4; ++mi) { \
    const unsigned short* p_ = &sA[c][(wm * 128 + 64 + mi * 16 + lr) * 64]; \
    avHI[mi][0] = *(const s16x8*)(p_ + c0); \
    avHI[mi][1] = *(const s16x8*)(p_ + c1); \
  } } while (0)

#define LDB0(c, P) do { \
  _Pragma("unroll") \
  for (int ni = 0; ni < 2; ++ni) { \
    const unsigned short* p_ = &sB[c][(wn * 64 + ni * 16 + lr) * 64]; \
    bv0[P][ni][0] = *(const s16x8*)(p_ + c0); \
    bv0[P][ni][1] = *(const s16x8*)(p_ + c1); \
  } } while (0)

#define LDB1(c) do { \
  _Pragma("unroll") \
  for (int ni = 0; ni < 2; ++ni) { \
    const unsigned short* p_ = &sB[c][(wn * 64 + 32 + ni * 16 + lr) * 64]; \
    bv1[ni][0] = *(const s16x8*)(p_ + c0); \
    bv1[ni][1] = *(const s16x8*)(p_ + c1); \
  } } while (0)

#define MMA_Q(ms, ns, AV, BV) do { \
  __builtin_amdgcn_s_setprio(1); \
  _Pragma("unroll") \
  for (int mi = 0; mi < 4; ++mi) \
    _Pragma("unroll") \
    for (int ni = 0; ni < 2; ++ni) { \
      acc[(ms) * 4 + mi][(ns) * 2 + ni] = __builtin_amdgcn_mfma_f32_16x16x32_bf16( \
          AV[mi][0], BV[ni][0], acc[(ms) * 4 + mi][(ns) * 2 + ni], 0, 0, 0); \
      acc[(ms) * 4 + mi][(ns) * 2 + ni] = __builtin_amdgcn_mfma_f32_16x16x32_bf16( \
          AV[mi][1], BV[ni][1], acc[(ms) * 4 + mi][(ns) * 2 + ni], 0, 0, 0); \
    } \
  __builtin_amdgcn_s_setprio(0); \
} while (0)

#define SB0() __builtin_amdgcn_sched_barrier(0)
#define BAR() __builtin_amdgcn_s_barrier()

  // ---- Prologue: stage tile 0, then pre-issue P1 fragments of tile 0 ----
  STG_B(0, 0, 0); STG_B(0, 0, 64); STG_B(0, 0, 128); STG_B(0, 0, 192);
  STG_A(0, 0, 0); STG_A(0, 0, 128); STG_A(0, 0, 64); STG_A(0, 0, 192);
  asm volatile("s_waitcnt vmcnt(0)" ::: "memory");
  BAR();
  LDALO(0, 0); LDB0(0, 0);   // 12 reads in flight entering the loop
  SB0();

  // GROUP(c, kt, PP, PPX): current buf c (ping PP), stages kt+1 into c^1, read-ahead into PPX.
  // DS FIFO at P1-wait: [avLO+bv0: 12 (prev P4/prologue)] [bv1: 4 (P1)] -> lgkmcnt(4)
  // at P2-wait: [bv1: 4] [avHI: 8] -> lgkmcnt(8) ; P3-wait: [avHI: 8] -> lgkmcnt(0)
  // VM FIFO: leftover A64,A192(kt) | P1 +B(kt+1)x4 -> vmcnt(4) | P2 +A(kt+1)x4 | P3-end vmcnt(2)
#define GROUP(c, kt, PP, PPX) do { \
  const bool st_ = (kt) + 1 < NKT; \
  /* P1 */ \
  LDB1(c); \
  if (st_) { STG_B((c) ^ 1, (kt) + 1, 0); STG_B((c) ^ 1, (kt) + 1, 64); \
             STG_B((c) ^ 1, (kt) + 1, 128); STG_B((c) ^ 1, (kt) + 1, 192); } \
  if (st_) { asm volatile("s_waitcnt vmcnt(4)" ::: "memory"); } \
  else     { asm volatile("s_waitcnt vmcnt(0)" ::: "memory"); } \
  BAR(); \
  asm volatile("s_waitcnt lgkmcnt(4)" ::: "memory"); SB0(); \
  MMA_Q(0, 0, avLO[PP], bv0[PP]); \
  BAR(); \
  /* P2 */ \
  LDAHI(c); \
  if (st_) { STG_A((c) ^ 1, (kt) + 1, 0); STG_A((c) ^ 1, (kt) + 1, 128); \
             STG_A((c) ^ 1, (kt) + 1, 64); STG_A((c) ^ 1, (kt) + 1, 192); } \
  BAR(); \
  asm volatile("s_waitcnt lgkmcnt(8)" ::: "memory"); SB0(); \
  MMA_Q(0, 1, avLO[PP], bv1); \
  BAR(); \
  /* P3: no new issues; avHI had a full phase to drain */ \
  asm volatile("s_waitcnt lgkmcnt(0)" ::: "memory"); SB0(); \
  MMA_Q(1, 1, avHI, bv1); \
  if (st_) { asm volatile("s_waitcnt vmcnt(2)" ::: "memory"); } \
  BAR(); \
  /* P4: read-ahead next tile's P1 fragments under this MFMA; no wait needed */ \
  if (st_) { LDALO((c) ^ 1, PPX); LDB0((c) ^ 1, PPX); SB0(); } \
  MMA_Q(1, 0, avHI, bv0[PP]); \
  BAR(); \
} while (0)

  for (int kt = 0; kt < NKT; kt += 2) {
    GROUP(0, kt, 0, 1);
    GROUP(1, kt + 1, 1, 0);
  }

  // Epilogue: C/D layout col = lane&15, row = (lane>>4)*4 + reg
  float bvv[4];
#pragma unroll
  for (int fn = 0; fn < 4; ++fn) bvv[fn] = bias[n0 + wn * 64 + fn * 16 + lr];
#pragma unroll
  for (int fm = 0; fm < 8; ++fm) {
    int row0 = m0 + wm * 128 + fm * 16 + lk * 4;
#pragma unroll
    for (int fn = 0; fn < 4; ++fn) {
      int col = n0 + wn * 64 + fn * 16 + lr;
#pragma unroll
      for (int r = 0; r < 4; ++r)
        C[(size_t)(row0 + r) * NDIM + col] = acc[fm][fn][r] + bvv[fn];
    }
  }
#undef GROUP
#undef MMA_Q
#undef LDB1
#undef LDB0
#undef LDAHI
#undef LDALO
#undef STG_A
#undef STG_B
#undef SB0
#undef BAR
}

// ---- exact-f32 fallback (used only if ws too small) ----
__global__ __launch_bounds__(256) void toep_f32_fallback(
    const float* __restrict__ X, const float* __restrict__ P,
    const float* __restrict__ bias, float* __restrict__ C)
{
  constexpr int TM = 64, TN = 64, TK = 32;
  __shared__ float xs[TM][TK + 1];
  __shared__ float win[TN + TK];
  int bm = blockIdx.x / (NDIM / TN);
  int bn = blockIdx.x % (NDIM / TN);
  int m0 = bm * TM, n0 = bn * TN;
  int t = (int)threadIdx.x;
  int tx = t & 15, ty = t >> 4;
  float acc[4][4] = {};
  for (int k0 = 0; k0 < KDIM; k0 += TK) {
    __syncthreads();
    for (int i = t; i < TM * TK; i += 256) {
      int r = i >> 5, c = i & 31;
      xs[r][c] = X[(size_t)(m0 + r) * KDIM + k0 + c];
    }
    if (t < TN + TK - 1) win[t] = P[(NDIM - 1) - n0 - (TN - 1) + k0 + t];
    __syncthreads();
    for (int kk = 0; kk < TK; ++kk) {
      float xv[4];
#pragma unroll
      for (int i = 0; i < 4; ++i) xv[i] = xs[ty * 4 + i][kk];
#pragma unroll
      for (int j = 0; j < 4; ++j) {
        float wv = win[kk + (TN - 1) - (tx * 4 + j)];
#pragma unroll
        for (int i = 0; i < 4; ++i) acc[i][j] += xv[i] * wv;
      }
    }
  }
#pragma unroll
  for (int i = 0; i < 4; ++i)
#pragma unroll
    for (int j = 0; j < 4; ++j)
      C[(size_t)(m0 + ty * 4 + i) * NDIM + n0 + tx * 4 + j] = acc[i][j] + bias[n0 + tx * 4 + j];
}

extern "C" void kernel_launch(void* const* d_in, const int* in_sizes, int n_in,
                              void* d_out, int out_size, void* d_ws, size_t ws_size,
                              hipStream_t stream) {
  const float* x = (const float*)d_in[0];
  const float* params = (const float*)d_in[1];
  const float* bias = (const float*)d_in[2];
  float* out = (float*)d_out;

  const size_t need = (size_t)MDIM * KDIM * 2 + (size_t)NDIM * KDIM * 2;  // 96 MiB
  if (ws_size >= need) {
    unsigned short* xb = (unsigned short*)d_ws;
    unsigned short* wb = xb + (size_t)MDIM * KDIM;
    cvt_x_kernel<<<2048, 256, 0, stream>>>(x, xb);
    build_w_kernel<<<2048, 256, 0, stream>>>(params, wb);
    toep_gemm8p<<<(MDIM / BM) * (NDIM / BN), 512, 0, stream>>>(xb, wb, bias, out);
  } else {
    toep_f32_fallback<<<(MDIM / 64) * (NDIM / 64), 256, 0, stream>>>(x, params, bias, out);
  }
}

// Round 5
// 318.059 us; speedup vs baseline: 2.0245x; 2.0245x over previous
//
#include <hip/hip_runtime.h>

typedef __attribute__((ext_vector_type(16))) float f32x16;
typedef __attribute__((ext_vector_type(8))) short s16x8;
typedef __attribute__((ext_vector_type(8))) unsigned short u16x8;

#define AS1 __attribute__((address_space(1)))
#define AS3 __attribute__((address_space(3)))

constexpr int MDIM = 8192;   // batch
constexpr int NDIM = 4096;   // out features
constexpr int KDIM = 4096;   // in features

constexpr int BM = 256, BN = 256, BK = 64;
constexpr int NKT = KDIM / BK;   // 64

__device__ __forceinline__ unsigned short f2bf(float f) {
  unsigned int u = __float_as_uint(f);
  u += 0x7fffu + ((u >> 16) & 1u);   // round-to-nearest-even
  return (unsigned short)(u >> 16);
}

__device__ __forceinline__ void gld_lds16(const unsigned short* g, unsigned short* l) {
  __builtin_amdgcn_global_load_lds((const AS1 void*)g, (AS3 void*)l, 16, 0, 0);
}

// ---- x f32 -> bf16 ----
__global__ void cvt_x_kernel(const float* __restrict__ x, unsigned short* __restrict__ xb) {
  const int n8 = MDIM * KDIM / 8;
  for (int i = blockIdx.x * blockDim.x + threadIdx.x; i < n8; i += gridDim.x * blockDim.x) {
    const float4* p = (const float4*)x + 2 * (size_t)i;
    float4 v0 = p[0], v1 = p[1];
    u16x8 r;
    r[0] = f2bf(v0.x); r[1] = f2bf(v0.y); r[2] = f2bf(v0.z); r[3] = f2bf(v0.w);
    r[4] = f2bf(v1.x); r[5] = f2bf(v1.y); r[6] = f2bf(v1.z); r[7] = f2bf(v1.w);
    *((u16x8*)xb + i) = r;
  }
}

// ---- W[o][k] = params[4095 - o + k], as bf16 [NDIM][KDIM] ----
__global__ void build_w_kernel(const float* __restrict__ params, unsigned short* __restrict__ wb) {
  const int n8 = NDIM * KDIM / 8;
  for (int i = blockIdx.x * blockDim.x + threadIdx.x; i < n8; i += gridDim.x * blockDim.x) {
    int o = i >> 9;
    int k0 = (i & 511) << 3;
    const float* p = params + (NDIM - 1 - o + k0);
    u16x8 r;
#pragma unroll
    for (int e = 0; e < 8; ++e) r[e] = f2bf(p[e]);
    *((u16x8*)wb + i) = r;
  }
}

// ================= 256x256 8-phase bf16 GEMM, 32x32x16 MFMA =================
// C = A * Bw^T + bias ; A[M][K], Bw[N][K] row-major bf16, C f32.
// LDS tile [256][64] bf16, XOR-swizzle col ^= (row&7)<<3 (elements).
// R2-proven skeleton: per K-tile 4 phases, 2 gld stages/phase,
// vmcnt(4)@P2 / vmcnt(2)@P4, 2 barriers/phase. P4 reuses bv0+av(half1).
__global__ __launch_bounds__(512, 2) void toep_gemm8p(
    const unsigned short* __restrict__ A,
    const unsigned short* __restrict__ Bw,
    const float* __restrict__ bias,
    float* __restrict__ C)
{
  __shared__ unsigned short sA[2][BM * BK];   // 64 KiB
  __shared__ unsigned short sB[2][BN * BK];   // 64 KiB

  constexpr int NBM = MDIM / BM;   // 32
  constexpr int NBN = NDIM / BN;   // 16
  constexpr int NWG = NBM * NBN;   // 512 (divisible by 8)
  int bid = (int)blockIdx.x;
  int swz = (bid & 7) * (NWG >> 3) + (bid >> 3);   // bijective: NWG % 8 == 0
  int bm = swz / NBN, bn = swz % NBN;
  int m0 = bm * BM, n0 = bn * BN;

  int t = (int)threadIdx.x;
  int lane = t & 63, wid = t >> 6;
  int wm = wid >> 2, wn = wid & 3;     // 2 (M) x 4 (N) wave grid; 128x64 per wave
  int l31 = lane & 31, hk = lane >> 5;

  // --- staging: dest linear t*16B, source col pre-swizzled ---
  int scol = (((t & 7) ^ ((t >> 3) & 7)) << 3);
  const unsigned short* gA = A + (size_t)(m0 + (t >> 3)) * KDIM + scol;
  const unsigned short* gB = Bw + (size_t)(n0 + (t >> 3)) * KDIM + scol;

#define STG_A(c, kt, R0) gld_lds16(gA + (size_t)(R0) * KDIM + (kt) * 64, &sA[c][(R0) * 64 + t * 8])
#define STG_B(c, kt, R0) gld_lds16(gB + (size_t)(R0) * KDIM + (kt) * 64, &sB[c][(R0) * 64 + t * 8])

  // --- ds_read fragment addressing (swizzled), 32x32x16 operands ---
  // lane's A/B row (within subtile) = l31; k = hk*8 + e; kstep ks covers k-cols ks*16..+15
  int aswz = (lane & 7) << 3;
  int cks[4];
#pragma unroll
  for (int ks = 0; ks < 4; ++ks) cks[ks] = (ks * 16 + hk * 8) ^ aswz;

  s16x8 av[2][4];    // 2 m-tiles x 4 ksteps (current half)
  s16x8 bv0[4];      // ntile 0, 4 ksteps (live P1->P4)
  s16x8 bv1[4];      // ntile 1
  f32x16 acc[4][2];  // 4 m-tiles x 2 n-tiles of 32x32
#pragma unroll
  for (int i = 0; i < 4; ++i)
#pragma unroll
    for (int j = 0; j < 2; ++j)
#pragma unroll
      for (int r = 0; r < 16; ++r) acc[i][j][r] = 0.f;

#define LDA_H(c, h) do { \
  _Pragma("unroll") \
  for (int mt = 0; mt < 2; ++mt) { \
    const unsigned short* p_ = &sA[c][(wm * 128 + (h) * 64 + mt * 32 + l31) * 64]; \
    _Pragma("unroll") \
    for (int ks = 0; ks < 4; ++ks) av[mt][ks] = *(const s16x8*)(p_ + cks[ks]); \
  } } while (0)

#define LDB_N(c, nt, BV) do { \
  const unsigned short* p_ = &sB[c][(wn * 64 + (nt) * 32 + l31) * 64]; \
  _Pragma("unroll") \
  for (int ks = 0; ks < 4; ++ks) BV[ks] = *(const s16x8*)(p_ + cks[ks]); \
} while (0)

#define MMA_PH(h, nt, BV) do { \
  __builtin_amdgcn_s_setprio(1); \
  _Pragma("unroll") \
  for (int ks = 0; ks < 4; ++ks) \
    _Pragma("unroll") \
    for (int mt = 0; mt < 2; ++mt) \
      acc[(h) * 2 + mt][nt] = __builtin_amdgcn_mfma_f32_32x32x16_bf16( \
          av[mt][ks], BV[ks], acc[(h) * 2 + mt][nt], 0, 0, 0); \
  __builtin_amdgcn_s_setprio(0); \
} while (0)

#define BAR() __builtin_amdgcn_s_barrier()

  // Prologue: stage tile 0 into buf0; leave A64,A192 in flight.
  STG_B(0, 0, 0); STG_B(0, 0, 64); STG_B(0, 0, 128); STG_B(0, 0, 192);
  STG_A(0, 0, 0); STG_A(0, 0, 128); STG_A(0, 0, 64); STG_A(0, 0, 192);
  asm volatile("s_waitcnt vmcnt(2)" ::: "memory");
  BAR();

  // VM FIFO invariant entering GROUP: outstanding = {A64(kt), A192(kt)}
  // P1 +B0,B64(kt+1); P2 +B128,B192, vmcnt(4) drains A64,A192(kt) [needed P3]
  // P3 +A0,A128; P4 +A64,A192, vmcnt(2) drains B*4+A0,A128 [needed next P1]
#define GROUP(c, kt) do { \
  const bool st_ = (kt) + 1 < NKT; \
  /* P1: half0 x n0 */ \
  LDA_H(c, 0); LDB_N(c, 0, bv0); \
  if (st_) { STG_B((c) ^ 1, (kt) + 1, 0); STG_B((c) ^ 1, (kt) + 1, 64); } \
  BAR(); \
  asm volatile("s_waitcnt lgkmcnt(0)"); \
  MMA_PH(0, 0, bv0); \
  BAR(); \
  /* P2: half0 x n1 */ \
  LDB_N(c, 1, bv1); \
  if (st_) { STG_B((c) ^ 1, (kt) + 1, 128); STG_B((c) ^ 1, (kt) + 1, 192); } \
  BAR(); \
  asm volatile("s_waitcnt lgkmcnt(0)"); \
  MMA_PH(0, 1, bv1); \
  if (st_) { asm volatile("s_waitcnt vmcnt(4)" ::: "memory"); } \
  else     { asm volatile("s_waitcnt vmcnt(0)" ::: "memory"); } \
  BAR(); \
  /* P3: half1 x n1 */ \
  LDA_H(c, 1); \
  if (st_) { STG_A((c) ^ 1, (kt) + 1, 0); STG_A((c) ^ 1, (kt) + 1, 128); } \
  BAR(); \
  asm volatile("s_waitcnt lgkmcnt(0)"); \
  MMA_PH(1, 1, bv1); \
  BAR(); \
  /* P4: half1 x n0 — no reads (reuse av half1 + bv0) */ \
  if (st_) { STG_A((c) ^ 1, (kt) + 1, 64); STG_A((c) ^ 1, (kt) + 1, 192); } \
  MMA_PH(1, 0, bv0); \
  if (st_) { asm volatile("s_waitcnt vmcnt(2)" ::: "memory"); } \
  BAR(); \
} while (0)

  for (int kt = 0; kt < NKT; kt += 2) {
    GROUP(0, kt);
    GROUP(1, kt + 1);
  }

  // Epilogue: 32x32 C/D: col = lane&31, row = (r&3) + 8*(r>>2) + 4*(lane>>5)
  float bvv[2];
#pragma unroll
  for (int nt = 0; nt < 2; ++nt) bvv[nt] = bias[n0 + wn * 64 + nt * 32 + l31];
#pragma unroll
  for (int mt = 0; mt < 4; ++mt) {
    int rowb = m0 + wm * 128 + mt * 32 + 4 * hk;
#pragma unroll
    for (int nt = 0; nt < 2; ++nt) {
      int col = n0 + wn * 64 + nt * 32 + l31;
#pragma unroll
      for (int r = 0; r < 16; ++r) {
        int row = rowb + (r & 3) + 8 * (r >> 2);
        C[(size_t)row * NDIM + col] = acc[mt][nt][r] + bvv[nt];
      }
    }
  }
#undef GROUP
#undef MMA_PH
#undef LDB_N
#undef LDA_H
#undef STG_A
#undef STG_B
#undef BAR
}

// ---- exact-f32 fallback (used only if ws too small) ----
__global__ __launch_bounds__(256) void toep_f32_fallback(
    const float* __restrict__ X, const float* __restrict__ P,
    const float* __restrict__ bias, float* __restrict__ C)
{
  constexpr int TM = 64, TN = 64, TK = 32;
  __shared__ float xs[TM][TK + 1];
  __shared__ float win[TN + TK];
  int bm = blockIdx.x / (NDIM / TN);
  int bn = blockIdx.x % (NDIM / TN);
  int m0 = bm * TM, n0 = bn * TN;
  int t = (int)threadIdx.x;
  int tx = t & 15, ty = t >> 4;
  float acc[4][4] = {};
  for (int k0 = 0; k0 < KDIM; k0 += TK) {
    __syncthreads();
    for (int i = t; i < TM * TK; i += 256) {
      int r = i >> 5, c = i & 31;
      xs[r][c] = X[(size_t)(m0 + r) * KDIM + k0 + c];
    }
    if (t < TN + TK - 1) win[t] = P[(NDIM - 1) - n0 - (TN - 1) + k0 + t];
    __syncthreads();
    for (int kk = 0; kk < TK; ++kk) {
      float xv[4];
#pragma unroll
      for (int i = 0; i < 4; ++i) xv[i] = xs[ty * 4 + i][kk];
#pragma unroll
      for (int j = 0; j < 4; ++j) {
        float wv = win[kk + (TN - 1) - (tx * 4 + j)];
#pragma unroll
        for (int i = 0; i < 4; ++i) acc[i][j] += xv[i] * wv;
      }
    }
  }
#pragma unroll
  for (int i = 0; i < 4; ++i)
#pragma unroll
    for (int j = 0; j < 4; ++j)
      C[(size_t)(m0 + ty * 4 + i) * NDIM + n0 + tx * 4 + j] = acc[i][j] + bias[n0 + tx * 4 + j];
}

extern "C" void kernel_launch(void* const* d_in, const int* in_sizes, int n_in,
                              void* d_out, int out_size, void* d_ws, size_t ws_size,
                              hipStream_t stream) {
  const float* x = (const float*)d_in[0];
  const float* params = (const float*)d_in[1];
  const float* bias = (const float*)d_in[2];
  float* out = (float*)d_out;

  const size_t need = (size_t)MDIM * KDIM * 2 + (size_t)NDIM * KDIM * 2;  // 96 MiB
  if (ws_size >= need) {
    unsigned short* xb = (unsigned short*)d_ws;
    unsigned short* wb = xb + (size_t)MDIM * KDIM;
    cvt_x_kernel<<<2048, 256, 0, stream>>>(x, xb);
    build_w_kernel<<<2048, 256, 0, stream>>>(params, wb);
    toep_gemm8p<<<(MDIM / BM) * (NDIM / BN), 512, 0, stream>>>(xb, wb, bias, out);
  } else {
    toep_f32_fallback<<<(MDIM / 64) * (NDIM / 64), 256, 0, stream>>>(x, params, bias, out);
  }
}

// Round 6
// 279.906 us; speedup vs baseline: 2.3005x; 1.1363x over previous
//
#include <hip/hip_runtime.h>

typedef __attribute__((ext_vector_type(4))) float f32x4;
typedef __attribute__((ext_vector_type(8))) short s16x8;
typedef __attribute__((ext_vector_type(8))) unsigned short u16x8;

#define AS1 __attribute__((address_space(1)))
#define AS3 __attribute__((address_space(3)))

constexpr int MDIM = 8192;   // batch
constexpr int NDIM = 4096;   // out features
constexpr int KDIM = 4096;   // in features

constexpr int BM = 256, BN = 256, BK = 64;
constexpr int NKT = KDIM / BK;   // 64

__device__ __forceinline__ unsigned short f2bf(float f) {
  unsigned int u = __float_as_uint(f);
  u += 0x7fffu + ((u >> 16) & 1u);   // round-to-nearest-even
  return (unsigned short)(u >> 16);
}

__device__ __forceinline__ void gld_lds16(const unsigned short* g, unsigned short* l) {
  __builtin_amdgcn_global_load_lds((const AS1 void*)g, (AS3 void*)l, 16, 0, 0);
}

// ---- x f32 -> bf16 ----
__global__ void cvt_x_kernel(const float* __restrict__ x, unsigned short* __restrict__ xb) {
  const int n8 = MDIM * KDIM / 8;
  for (int i = blockIdx.x * blockDim.x + threadIdx.x; i < n8; i += gridDim.x * blockDim.x) {
    const float4* p = (const float4*)x + 2 * (size_t)i;
    float4 v0 = p[0], v1 = p[1];
    u16x8 r;
    r[0] = f2bf(v0.x); r[1] = f2bf(v0.y); r[2] = f2bf(v0.z); r[3] = f2bf(v0.w);
    r[4] = f2bf(v1.x); r[5] = f2bf(v1.y); r[6] = f2bf(v1.z); r[7] = f2bf(v1.w);
    *((u16x8*)xb + i) = r;
  }
}

// ---- W[o][k] = params[4095 - o + k], as bf16 [NDIM][KDIM] ----
__global__ void build_w_kernel(const float* __restrict__ params, unsigned short* __restrict__ wb) {
  const int n8 = NDIM * KDIM / 8;
  for (int i = blockIdx.x * blockDim.x + threadIdx.x; i < n8; i += gridDim.x * blockDim.x) {
    int o = i >> 9;
    int k0 = (i & 511) << 3;
    const float* p = params + (NDIM - 1 - o + k0);
    u16x8 r;
#pragma unroll
    for (int e = 0; e < 8; ++e) r[e] = f2bf(p[e]);
    *((u16x8*)wb + i) = r;
  }
}

// ========== 256x256 bf16 GEMM, 1 barrier per K-tile (free-running waves) ==========
// C = A * Bw^T + bias ; A[M][K], Bw[N][K] row-major bf16, C f32.
// LDS tile [256][64] bf16, XOR-swizzle col ^= (row&7)<<3 (elements).
// R2's exact ds_read/MFMA/DMA instructions, reordered: all reads up-front with
// counted lgkmcnt, one vmcnt(0)+s_barrier per K-tile. Wave-level overlap hides drains.
__global__ __launch_bounds__(512, 2) void toep_gemm1b(
    const unsigned short* __restrict__ A,
    const unsigned short* __restrict__ Bw,
    const float* __restrict__ bias,
    float* __restrict__ C)
{
  __shared__ unsigned short sA[2][BM * BK];   // 64 KiB
  __shared__ unsigned short sB[2][BN * BK];   // 64 KiB

  constexpr int NBM = MDIM / BM;   // 32
  constexpr int NBN = NDIM / BN;   // 16
  constexpr int NWG = NBM * NBN;   // 512 (divisible by 8)
  int bid = (int)blockIdx.x;
  int swz = (bid & 7) * (NWG >> 3) + (bid >> 3);   // bijective: NWG % 8 == 0
  int bm = swz / NBN, bn = swz % NBN;
  int m0 = bm * BM, n0 = bn * BN;

  int t = (int)threadIdx.x;
  int lane = t & 63, wid = t >> 6;
  int wm = wid >> 2, wn = wid & 3;     // 2 (M) x 4 (N) wave grid; 128x64 per wave
  int lr = lane & 15, lk = lane >> 4;

  // --- staging: dest linear t*16B, source col pre-swizzled ---
  int scol = (((t & 7) ^ ((t >> 3) & 7)) << 3);
  const unsigned short* gA = A + (size_t)(m0 + (t >> 3)) * KDIM + scol;
  const unsigned short* gB = Bw + (size_t)(n0 + (t >> 3)) * KDIM + scol;

#define STG_A(c, kt, R0) gld_lds16(gA + (size_t)(R0) * KDIM + (kt) * 64, &sA[c][(R0) * 64 + t * 8])
#define STG_B(c, kt, R0) gld_lds16(gB + (size_t)(R0) * KDIM + (kt) * 64, &sB[c][(R0) * 64 + t * 8])

  // --- ds_read fragment addressing (swizzled) --- [R2-proven: 0 conflicts]
  int aswz = (lr & 7) << 3;
  int c0 = (lk * 8) ^ aswz;          // ks=0 physical col (elements)
  int c1 = (32 + lk * 8) ^ aswz;     // ks=1

  s16x8 av[4][2], bvA[2][2], bvB[2][2];
  f32x4 acc[8][4];
#pragma unroll
  for (int i = 0; i < 8; ++i)
#pragma unroll
    for (int j = 0; j < 4; ++j) acc[i][j] = (f32x4){0.f, 0.f, 0.f, 0.f};

#define LDA_SUB(c, msub) do { \
  _Pragma("unroll") \
  for (int mi = 0; mi < 4; ++mi) { \
    const unsigned short* p_ = &sA[c][(wm * 128 + (msub) * 64 + mi * 16 + lr) * 64]; \
    av[mi][0] = *(const s16x8*)(p_ + c0); \
    av[mi][1] = *(const s16x8*)(p_ + c1); \
  } } while (0)

#define LDB_GRP(c, nsub, BV) do { \
  _Pragma("unroll") \
  for (int ni = 0; ni < 2; ++ni) { \
    const unsigned short* p_ = &sB[c][(wn * 64 + (nsub) * 32 + ni * 16 + lr) * 64]; \
    BV[ni][0] = *(const s16x8*)(p_ + c0); \
    BV[ni][1] = *(const s16x8*)(p_ + c1); \
  } } while (0)

#define MMA_Q(msub, nsub, BV) do { \
  __builtin_amdgcn_s_setprio(1); \
  _Pragma("unroll") \
  for (int mi = 0; mi < 4; ++mi) \
    _Pragma("unroll") \
    for (int ni = 0; ni < 2; ++ni) { \
      acc[(msub) * 4 + mi][(nsub) * 2 + ni] = __builtin_amdgcn_mfma_f32_16x16x32_bf16( \
          av[mi][0], BV[ni][0], acc[(msub) * 4 + mi][(nsub) * 2 + ni], 0, 0, 0); \
      acc[(msub) * 4 + mi][(nsub) * 2 + ni] = __builtin_amdgcn_mfma_f32_16x16x32_bf16( \
          av[mi][1], BV[ni][1], acc[(msub) * 4 + mi][(nsub) * 2 + ni], 0, 0, 0); \
    } \
  __builtin_amdgcn_s_setprio(0); \
} while (0)

#define SB0() __builtin_amdgcn_sched_barrier(0)
#define BAR() __builtin_amdgcn_s_barrier()

  // Prologue: stage tile 0 into buf0, full drain, barrier.
  STG_B(0, 0, 0); STG_B(0, 0, 64); STG_B(0, 0, 128); STG_B(0, 0, 192);
  STG_A(0, 0, 0); STG_A(0, 0, 64); STG_A(0, 0, 128); STG_A(0, 0, 192);
  asm volatile("s_waitcnt vmcnt(0)" ::: "memory");
  BAR();

  // TILE(c, kt): read buf c, stage kt+1 into buf c^1. ONE barrier at end.
  // DS FIFO: avLO(8), bvA(4) | bvB(4)  -> lgkm(4) covers avLO+bvA
  // Safety: each wave's lgkmcnt(0) (before Q11) completes ALL its reads of c
  // before it passes the end barrier; DMA into c is only issued after that
  // barrier by any wave. vmcnt(0) at tile end drains ~1-tile-old DMA (free).
#define TILE(c, kt) do { \
  const bool st_ = (kt) + 1 < NKT; \
  if (st_) { \
    STG_B((c) ^ 1, (kt) + 1, 0); STG_B((c) ^ 1, (kt) + 1, 64); \
    STG_B((c) ^ 1, (kt) + 1, 128); STG_B((c) ^ 1, (kt) + 1, 192); \
    STG_A((c) ^ 1, (kt) + 1, 0); STG_A((c) ^ 1, (kt) + 1, 64); \
    STG_A((c) ^ 1, (kt) + 1, 128); STG_A((c) ^ 1, (kt) + 1, 192); \
  } \
  LDA_SUB(c, 0); LDB_GRP(c, 0, bvA); SB0(); \
  LDB_GRP(c, 1, bvB); \
  asm volatile("s_waitcnt lgkmcnt(4)" ::: "memory"); SB0(); \
  MMA_Q(0, 0, bvA); \
  asm volatile("s_waitcnt lgkmcnt(0)" ::: "memory"); SB0(); \
  MMA_Q(0, 1, bvB); \
  LDA_SUB(c, 1); \
  asm volatile("s_waitcnt lgkmcnt(0)" ::: "memory"); SB0(); \
  MMA_Q(1, 1, bvB); \
  MMA_Q(1, 0, bvA); \
  asm volatile("s_waitcnt vmcnt(0)" ::: "memory"); \
  BAR(); \
} while (0)

  for (int kt = 0; kt < NKT; kt += 2) {
    TILE(0, kt);
    TILE(1, kt + 1);
  }

  // Epilogue: C/D layout col = lane&15, row = (lane>>4)*4 + reg
  float bvv[4];
#pragma unroll
  for (int fn = 0; fn < 4; ++fn) bvv[fn] = bias[n0 + wn * 64 + fn * 16 + lr];
#pragma unroll
  for (int fm = 0; fm < 8; ++fm) {
    int row0 = m0 + wm * 128 + fm * 16 + lk * 4;
#pragma unroll
    for (int fn = 0; fn < 4; ++fn) {
      int col = n0 + wn * 64 + fn * 16 + lr;
#pragma unroll
      for (int r = 0; r < 4; ++r)
        C[(size_t)(row0 + r) * NDIM + col] = acc[fm][fn][r] + bvv[fn];
    }
  }
#undef TILE
#undef MMA_Q
#undef LDB_GRP
#undef LDA_SUB
#undef STG_A
#undef STG_B
#undef SB0
#undef BAR
}

// ---- exact-f32 fallback (used only if ws too small) ----
__global__ __launch_bounds__(256) void toep_f32_fallback(
    const float* __restrict__ X, const float* __restrict__ P,
    const float* __restrict__ bias, float* __restrict__ C)
{
  constexpr int TM = 64, TN = 64, TK = 32;
  __shared__ float xs[TM][TK + 1];
  __shared__ float win[TN + TK];
  int bm = blockIdx.x / (NDIM / TN);
  int bn = blockIdx.x % (NDIM / TN);
  int m0 = bm * TM, n0 = bn * TN;
  int t = (int)threadIdx.x;
  int tx = t & 15, ty = t >> 4;
  float acc[4][4] = {};
  for (int k0 = 0; k0 < KDIM; k0 += TK) {
    __syncthreads();
    for (int i = t; i < TM * TK; i += 256) {
      int r = i >> 5, c = i & 31;
      xs[r][c] = X[(size_t)(m0 + r) * KDIM + k0 + c];
    }
    if (t < TN + TK - 1) win[t] = P[(NDIM - 1) - n0 - (TN - 1) + k0 + t];
    __syncthreads();
    for (int kk = 0; kk < TK; ++kk) {
      float xv[4];
#pragma unroll
      for (int i = 0; i < 4; ++i) xv[i] = xs[ty * 4 + i][kk];
#pragma unroll
      for (int j = 0; j < 4; ++j) {
        float wv = win[kk + (TN - 1) - (tx * 4 + j)];
#pragma unroll
        for (int i = 0; i < 4; ++i) acc[i][j] += xv[i] * wv;
      }
    }
  }
#pragma unroll
  for (int i = 0; i < 4; ++i)
#pragma unroll
    for (int j = 0; j < 4; ++j)
      C[(size_t)(m0 + ty * 4 + i) * NDIM + n0 + tx * 4 + j] = acc[i][j] + bias[n0 + tx * 4 + j];
}

extern "C" void kernel_launch(void* const* d_in, const int* in_sizes, int n_in,
                              void* d_out, int out_size, void* d_ws, size_t ws_size,
                              hipStream_t stream) {
  const float* x = (const float*)d_in[0];
  const float* params = (const float*)d_in[1];
  const float* bias = (const float*)d_in[2];
  float* out = (float*)d_out;

  const size_t need = (size_t)MDIM * KDIM * 2 + (size_t)NDIM * KDIM * 2;  // 96 MiB
  if (ws_size >= need) {
    unsigned short* xb = (unsigned short*)d_ws;
    unsigned short* wb = xb + (size_t)MDIM * KDIM;
    cvt_x_kernel<<<2048, 256, 0, stream>>>(x, xb);
    build_w_kernel<<<2048, 256, 0, stream>>>(params, wb);
    toep_gemm1b<<<(MDIM / BM) * (NDIM / BN), 512, 0, stream>>>(xb, wb, bias, out);
  } else {
    toep_f32_fallback<<<(MDIM / 64) * (NDIM / 64), 256, 0, stream>>>(x, params, bias, out);
  }
}

// Round 7
// 175.913 us; speedup vs baseline: 3.6605x; 1.5912x over previous
//
#include <hip/hip_runtime.h>

typedef __attribute__((ext_vector_type(4))) int i32x4;
typedef __attribute__((ext_vector_type(4))) float f32x4;

#define AS1 __attribute__((address_space(1)))
#define AS3 __attribute__((address_space(3)))

constexpr int MDIM = 8192;   // batch
constexpr int NDIM = 4096;   // out features
constexpr int KDIM = 4096;   // in features

constexpr int BM = 256, BN = 256, BKB = 128;   // BKB = K-bytes (=128 i8 elems) per tile
constexpr int NKT = KDIM / BKB;                // 32

__device__ __forceinline__ void gld_lds16(const signed char* g, signed char* l) {
  __builtin_amdgcn_global_load_lds((const AS1 void*)g, (AS3 void*)l, 16, 0, 0);
}

__device__ __forceinline__ int q8(float v, float inv) {
  int q = __float2int_rn(v * inv);
  return q;   // |v*inv| <= 127 by construction of inv
}

// ---- w scale: swbuf[0] = max|params|/127, swbuf[1] = 127/max ----
__global__ void wscale_kernel(const float* __restrict__ params, float* __restrict__ swbuf) {
  int t = (int)threadIdx.x;
  float m = 0.f;
  for (int i = t; i < NDIM + KDIM - 1; i += 256) m = fmaxf(m, fabsf(params[i]));
#pragma unroll
  for (int off = 32; off >= 1; off >>= 1) m = fmaxf(m, __shfl_xor(m, off));
  __shared__ float red[4];
  if ((t & 63) == 0) red[t >> 6] = m;
  __syncthreads();
  if (t == 0) {
    m = fmaxf(fmaxf(red[0], red[1]), fmaxf(red[2], red[3]));
    m = fmaxf(m, 1e-30f);
    swbuf[0] = m * (1.0f / 127.0f);
    swbuf[1] = 127.0f / m;
  }
}

// ---- per-row x quantization: one block per row ----
__global__ __launch_bounds__(256) void quant_x_kernel(
    const float* __restrict__ x, signed char* __restrict__ xq, float* __restrict__ sxr) {
  int row = (int)blockIdx.x;
  int t = (int)threadIdx.x;
  const float4* px = (const float4*)(x + (size_t)row * KDIM) + t * 4;
  float4 v[4];
#pragma unroll
  for (int i = 0; i < 4; ++i) v[i] = px[i];
  float m = 0.f;
#pragma unroll
  for (int i = 0; i < 4; ++i)
    m = fmaxf(fmaxf(fmaxf(fabsf(v[i].x), fabsf(v[i].y)), fmaxf(fabsf(v[i].z), fabsf(v[i].w))), m);
#pragma unroll
  for (int off = 32; off >= 1; off >>= 1) m = fmaxf(m, __shfl_xor(m, off));
  __shared__ float red[4];
  if ((t & 63) == 0) red[t >> 6] = m;
  __syncthreads();
  m = fmaxf(fmaxf(red[0], red[1]), fmaxf(red[2], red[3]));
  m = fmaxf(m, 1e-30f);
  float inv = 127.0f / m;
  if (t == 0) sxr[row] = m * (1.0f / 127.0f);
  i32x4 w;
#pragma unroll
  for (int i = 0; i < 4; ++i) {
    int q0 = q8(v[i].x, inv), q1 = q8(v[i].y, inv), q2 = q8(v[i].z, inv), q3 = q8(v[i].w, inv);
    w[i] = (q0 & 0xff) | ((q1 & 0xff) << 8) | ((q2 & 0xff) << 16) | ((q3 & 0xff) << 24);
  }
  *(i32x4*)(xq + (size_t)row * KDIM + t * 16) = w;
}

// ---- Wq[o][k] = quant(params[4095 - o + k]) ----
__global__ __launch_bounds__(256) void build_wq_kernel(
    const float* __restrict__ params, const float* __restrict__ swbuf,
    signed char* __restrict__ wq) {
  float inv = swbuf[1];
  int i = blockIdx.x * 256 + (int)threadIdx.x;   // 16 elems per thread
  int o = i >> 8;
  int k0 = (i & 255) << 4;
  const float* p = params + (NDIM - 1 - o + k0);
  i32x4 w;
#pragma unroll
  for (int j = 0; j < 4; ++j) {
    int q0 = q8(p[4 * j + 0], inv), q1 = q8(p[4 * j + 1], inv);
    int q2 = q8(p[4 * j + 2], inv), q3 = q8(p[4 * j + 3], inv);
    w[j] = (q0 & 0xff) | ((q1 & 0xff) << 8) | ((q2 & 0xff) << 16) | ((q3 & 0xff) << 24);
  }
  *(i32x4*)(wq + (size_t)o * KDIM + k0) = w;
}

// ========== 256x256 i8 GEMM, 1 barrier per K-tile (R6 schedule, i8 types) ==========
// C = (Aq * Wq^T) * sx[row] * sw + bias ; Aq[M][K], Wq[N][K] row-major i8, C f32.
// LDS tile [256][128B], 16B slots, XOR-swizzle slot ^= (row&7)  [R2/R6-measured 0 conflicts].
__global__ __launch_bounds__(512, 2) void toep_gemm_i8(
    const signed char* __restrict__ A,
    const signed char* __restrict__ Bw,
    const float* __restrict__ bias,
    const float* __restrict__ sxr,
    const float* __restrict__ swbuf,
    float* __restrict__ C)
{
  __shared__ signed char sA[2][BM * BKB];   // 64 KiB
  __shared__ signed char sB[2][BN * BKB];   // 64 KiB

  constexpr int NBM = MDIM / BM;   // 32
  constexpr int NBN = NDIM / BN;   // 16
  constexpr int NWG = NBM * NBN;   // 512
  int bid = (int)blockIdx.x;
  int swz = (bid & 7) * (NWG >> 3) + (bid >> 3);
  int bm = swz / NBN, bn = swz % NBN;
  int m0 = bm * BM, n0 = bn * BN;

  int t = (int)threadIdx.x;
  int lane = t & 63, wid = t >> 6;
  int wm = wid >> 2, wn = wid & 3;     // 2 (M) x 4 (N) waves; 128x64 per wave
  int lr = lane & 15, lk = lane >> 4;

  // staging: dest linear t*16B, source slot pre-swizzled
  int scol = (((t & 7) ^ ((t >> 3) & 7)) << 4);   // bytes
  const signed char* gA = A + (size_t)(m0 + (t >> 3)) * KDIM + scol;
  const signed char* gB = Bw + (size_t)(n0 + (t >> 3)) * KDIM + scol;

#define STG_A(c, kt, R0) gld_lds16(gA + (size_t)(R0) * KDIM + (kt) * BKB, &sA[c][(R0) * BKB + t * 16])
#define STG_B(c, kt, R0) gld_lds16(gB + (size_t)(R0) * KDIM + (kt) * BKB, &sB[c][(R0) * BKB + t * 16])

  // ds_read fragment addressing (swizzled, bytes)
  int aswz = (lr & 7) << 4;
  int c0 = (lk * 16) ^ aswz;        // kstep 0: k-bytes 0..63
  int c1 = (64 + lk * 16) ^ aswz;   // kstep 1: k-bytes 64..127

  i32x4 av[4][2], bvA[2][2], bvB[2][2];
  i32x4 acc[8][4];
#pragma unroll
  for (int i = 0; i < 8; ++i)
#pragma unroll
    for (int j = 0; j < 4; ++j) acc[i][j] = (i32x4){0, 0, 0, 0};

#define LDA_SUB(c, msub) do { \
  _Pragma("unroll") \
  for (int mi = 0; mi < 4; ++mi) { \
    const signed char* p_ = &sA[c][(wm * 128 + (msub) * 64 + mi * 16 + lr) * BKB]; \
    av[mi][0] = *(const i32x4*)(p_ + c0); \
    av[mi][1] = *(const i32x4*)(p_ + c1); \
  } } while (0)

#define LDB_GRP(c, nsub, BV) do { \
  _Pragma("unroll") \
  for (int ni = 0; ni < 2; ++ni) { \
    const signed char* p_ = &sB[c][(wn * 64 + (nsub) * 32 + ni * 16 + lr) * BKB]; \
    BV[ni][0] = *(const i32x4*)(p_ + c0); \
    BV[ni][1] = *(const i32x4*)(p_ + c1); \
  } } while (0)

#define MMA_Q(msub, nsub, BV) do { \
  __builtin_amdgcn_s_setprio(1); \
  _Pragma("unroll") \
  for (int mi = 0; mi < 4; ++mi) \
    _Pragma("unroll") \
    for (int ni = 0; ni < 2; ++ni) { \
      acc[(msub) * 4 + mi][(nsub) * 2 + ni] = __builtin_amdgcn_mfma_i32_16x16x64_i8( \
          av[mi][0], BV[ni][0], acc[(msub) * 4 + mi][(nsub) * 2 + ni], 0, 0, 0); \
      acc[(msub) * 4 + mi][(nsub) * 2 + ni] = __builtin_amdgcn_mfma_i32_16x16x64_i8( \
          av[mi][1], BV[ni][1], acc[(msub) * 4 + mi][(nsub) * 2 + ni], 0, 0, 0); \
    } \
  __builtin_amdgcn_s_setprio(0); \
} while (0)

#define SB0() __builtin_amdgcn_sched_barrier(0)
#define BAR() __builtin_amdgcn_s_barrier()

  // Prologue: stage tile 0 into buf0, full drain, barrier.
  STG_B(0, 0, 0); STG_B(0, 0, 64); STG_B(0, 0, 128); STG_B(0, 0, 192);
  STG_A(0, 0, 0); STG_A(0, 0, 64); STG_A(0, 0, 128); STG_A(0, 0, 192);
  asm volatile("s_waitcnt vmcnt(0)" ::: "memory");
  BAR();

#define TILE(c, kt) do { \
  const bool st_ = (kt) + 1 < NKT; \
  if (st_) { \
    STG_B((c) ^ 1, (kt) + 1, 0); STG_B((c) ^ 1, (kt) + 1, 64); \
    STG_B((c) ^ 1, (kt) + 1, 128); STG_B((c) ^ 1, (kt) + 1, 192); \
    STG_A((c) ^ 1, (kt) + 1, 0); STG_A((c) ^ 1, (kt) + 1, 64); \
    STG_A((c) ^ 1, (kt) + 1, 128); STG_A((c) ^ 1, (kt) + 1, 192); \
  } \
  LDA_SUB(c, 0); LDB_GRP(c, 0, bvA); SB0(); \
  LDB_GRP(c, 1, bvB); \
  asm volatile("s_waitcnt lgkmcnt(4)" ::: "memory"); SB0(); \
  MMA_Q(0, 0, bvA); \
  asm volatile("s_waitcnt lgkmcnt(0)" ::: "memory"); SB0(); \
  MMA_Q(0, 1, bvB); \
  LDA_SUB(c, 1); \
  asm volatile("s_waitcnt lgkmcnt(0)" ::: "memory"); SB0(); \
  MMA_Q(1, 1, bvB); \
  MMA_Q(1, 0, bvA); \
  asm volatile("s_waitcnt vmcnt(0)" ::: "memory"); \
  BAR(); \
} while (0)

  for (int kt = 0; kt < NKT; kt += 2) {
    TILE(0, kt);
    TILE(1, kt + 1);
  }

  // Epilogue: C/D col = lane&15, row = (lane>>4)*4 + reg; out = acc*sx[row]*sw + bias
  float sw = swbuf[0];
  float bvv[4];
#pragma unroll
  for (int fn = 0; fn < 4; ++fn) bvv[fn] = bias[n0 + wn * 64 + fn * 16 + lr];
#pragma unroll
  for (int fm = 0; fm < 8; ++fm) {
    int row0 = m0 + wm * 128 + fm * 16 + lk * 4;
    float sx_[4];
#pragma unroll
    for (int r = 0; r < 4; ++r) sx_[r] = sxr[row0 + r] * sw;
#pragma unroll
    for (int fn = 0; fn < 4; ++fn) {
      int col = n0 + wn * 64 + fn * 16 + lr;
#pragma unroll
      for (int r = 0; r < 4; ++r)
        C[(size_t)(row0 + r) * NDIM + col] = (float)acc[fm][fn][r] * sx_[r] + bvv[fn];
    }
  }
#undef TILE
#undef MMA_Q
#undef LDB_GRP
#undef LDA_SUB
#undef STG_A
#undef STG_B
#undef SB0
#undef BAR
}

// ---- exact-f32 fallback (used only if ws too small) ----
__global__ __launch_bounds__(256) void toep_f32_fallback(
    const float* __restrict__ X, const float* __restrict__ P,
    const float* __restrict__ bias, float* __restrict__ C)
{
  constexpr int TM = 64, TN = 64, TK = 32;
  __shared__ float xs[TM][TK + 1];
  __shared__ float win[TN + TK];
  int bm = blockIdx.x / (NDIM / TN);
  int bn = blockIdx.x % (NDIM / TN);
  int m0 = bm * TM, n0 = bn * TN;
  int t = (int)threadIdx.x;
  int tx = t & 15, ty = t >> 4;
  float acc[4][4] = {};
  for (int k0 = 0; k0 < KDIM; k0 += TK) {
    __syncthreads();
    for (int i = t; i < TM * TK; i += 256) {
      int r = i >> 5, c = i & 31;
      xs[r][c] = X[(size_t)(m0 + r) * KDIM + k0 + c];
    }
    if (t < TN + TK - 1) win[t] = P[(NDIM - 1) - n0 - (TN - 1) + k0 + t];
    __syncthreads();
    for (int kk = 0; kk < TK; ++kk) {
      float xv[4];
#pragma unroll
      for (int i = 0; i < 4; ++i) xv[i] = xs[ty * 4 + i][kk];
#pragma unroll
      for (int j = 0; j < 4; ++j) {
        float wv = win[kk + (TN - 1) - (tx * 4 + j)];
#pragma unroll
        for (int i = 0; i < 4; ++i) acc[i][j] += xv[i] * wv;
      }
    }
  }
#pragma unroll
  for (int i = 0; i < 4; ++i)
#pragma unroll
    for (int j = 0; j < 4; ++j)
      C[(size_t)(m0 + ty * 4 + i) * NDIM + n0 + tx * 4 + j] = acc[i][j] + bias[n0 + tx * 4 + j];
}

extern "C" void kernel_launch(void* const* d_in, const int* in_sizes, int n_in,
                              void* d_out, int out_size, void* d_ws, size_t ws_size,
                              hipStream_t stream) {
  const float* x = (const float*)d_in[0];
  const float* params = (const float*)d_in[1];
  const float* bias = (const float*)d_in[2];
  float* out = (float*)d_out;

  const size_t xq_off = 0;
  const size_t wq_off = (size_t)MDIM * KDIM;                 // 33554432
  const size_t sx_off = wq_off + (size_t)NDIM * KDIM;        // +16777216
  const size_t sw_off = sx_off + (size_t)MDIM * 4;           // +32768
  const size_t need = sw_off + 64;

  if (ws_size >= need) {
    signed char* xq = (signed char*)d_ws + xq_off;
    signed char* wq = (signed char*)d_ws + wq_off;
    float* sxr = (float*)((char*)d_ws + sx_off);
    float* swbuf = (float*)((char*)d_ws + sw_off);
    wscale_kernel<<<1, 256, 0, stream>>>(params, swbuf);
    quant_x_kernel<<<MDIM, 256, 0, stream>>>(x, xq, sxr);
    build_wq_kernel<<<NDIM * KDIM / 16 / 256, 256, 0, stream>>>(params, swbuf, wq);
    toep_gemm_i8<<<(MDIM / BM) * (NDIM / BN), 512, 0, stream>>>(xq, wq, bias, sxr, swbuf, out);
  } else {
    toep_f32_fallback<<<(MDIM / 64) * (NDIM / 64), 256, 0, stream>>>(x, params, bias, out);
  }
}

// Round 9
// 173.584 us; speedup vs baseline: 3.7096x; 1.0134x over previous
//
#include <hip/hip_runtime.h>

typedef __attribute__((ext_vector_type(4))) int i32x4;
typedef __attribute__((ext_vector_type(4))) float f32x4;

#define AS1 __attribute__((address_space(1)))
#define AS3 __attribute__((address_space(3)))

constexpr int MDIM = 8192;   // batch
constexpr int NDIM = 4096;   // out features
constexpr int KDIM = 4096;   // in features

constexpr int BM = 256, BN = 256, BKB = 128;   // BKB = K-bytes (=128 i8) per tile
constexpr int NKT = KDIM / BKB;                // 32

__device__ __forceinline__ void gld_lds16(const signed char* g, signed char* l) {
  __builtin_amdgcn_global_load_lds((const AS1 void*)g, (AS3 void*)l, 16, 0, 0);
}

__device__ __forceinline__ int q8(float v, float inv) {
  return __float2int_rn(v * inv);
}

// ---- w scale: swbuf[0] = max|params|/127, swbuf[1] = 127/max ----
__global__ void wscale_kernel(const float* __restrict__ params, float* __restrict__ swbuf) {
  int t = (int)threadIdx.x;
  float m = 0.f;
  for (int i = t; i < NDIM + KDIM - 1; i += 256) m = fmaxf(m, fabsf(params[i]));
#pragma unroll
  for (int off = 32; off >= 1; off >>= 1) m = fmaxf(m, __shfl_xor(m, off));
  __shared__ float red[4];
  if ((t & 63) == 0) red[t >> 6] = m;
  __syncthreads();
  if (t == 0) {
    m = fmaxf(fmaxf(red[0], red[1]), fmaxf(red[2], red[3]));
    m = fmaxf(m, 1e-30f);
    swbuf[0] = m * (1.0f / 127.0f);
    swbuf[1] = 127.0f / m;
  }
}

// ---- per-row x quantization: one block per row ----
__global__ __launch_bounds__(256) void quant_x_kernel(
    const float* __restrict__ x, signed char* __restrict__ xq, float* __restrict__ sxr) {
  int row = (int)blockIdx.x;
  int t = (int)threadIdx.x;
  const float4* px = (const float4*)(x + (size_t)row * KDIM) + t * 4;
  float4 v[4];
#pragma unroll
  for (int i = 0; i < 4; ++i) v[i] = px[i];
  float m = 0.f;
#pragma unroll
  for (int i = 0; i < 4; ++i)
    m = fmaxf(fmaxf(fmaxf(fabsf(v[i].x), fabsf(v[i].y)), fmaxf(fabsf(v[i].z), fabsf(v[i].w))), m);
#pragma unroll
  for (int off = 32; off >= 1; off >>= 1) m = fmaxf(m, __shfl_xor(m, off));
  __shared__ float red[4];
  if ((t & 63) == 0) red[t >> 6] = m;
  __syncthreads();
  m = fmaxf(fmaxf(red[0], red[1]), fmaxf(red[2], red[3]));
  m = fmaxf(m, 1e-30f);
  float inv = 127.0f / m;
  if (t == 0) sxr[row] = m * (1.0f / 127.0f);
  i32x4 w;
#pragma unroll
  for (int i = 0; i < 4; ++i) {
    int q0 = q8(v[i].x, inv), q1 = q8(v[i].y, inv), q2 = q8(v[i].z, inv), q3 = q8(v[i].w, inv);
    w[i] = (q0 & 0xff) | ((q1 & 0xff) << 8) | ((q2 & 0xff) << 16) | ((q3 & 0xff) << 24);
  }
  *(i32x4*)(xq + (size_t)row * KDIM + t * 16) = w;
}

// ---- Wq[o][k] = quant(params[4095 - o + k]) ----
__global__ __launch_bounds__(256) void build_wq_kernel(
    const float* __restrict__ params, const float* __restrict__ swbuf,
    signed char* __restrict__ wq) {
  float inv = swbuf[1];
  int i = blockIdx.x * 256 + (int)threadIdx.x;   // 16 elems per thread
  int o = i >> 8;
  int k0 = (i & 255) << 4;
  const float* p = params + (NDIM - 1 - o + k0);
  i32x4 w;
#pragma unroll
  for (int j = 0; j < 4; ++j) {
    int q0 = q8(p[4 * j + 0], inv), q1 = q8(p[4 * j + 1], inv);
    int q2 = q8(p[4 * j + 2], inv), q3 = q8(p[4 * j + 3], inv);
    w[j] = (q0 & 0xff) | ((q1 & 0xff) << 8) | ((q2 & 0xff) << 16) | ((q3 & 0xff) << 24);
  }
  *(i32x4*)(wq + (size_t)o * KDIM + k0) = w;
}

// ========== 256x256 i8 GEMM, 16x16x64 MFMA, quadrant one-ahead pipeline ==========
// C = (Aq * Wq^T) * sx[row] * sw + bias.
// LDS tile [256 rows][128 B], 16-B slots, phys slot = logical ^ (row&7)
// [R7-measured ZERO conflicts with this exact read geometry].
// Quadrants Q00->Q01->Q10->Q11; Q0 operands read-ahead at prev tile's P3
// AFTER {vmcnt(0); s_barrier} (fixes R8's cross-tile race).
__global__ __launch_bounds__(512, 2) void toep_gemm_i8(
    const signed char* __restrict__ A,
    const signed char* __restrict__ Bw,
    const float* __restrict__ bias,
    const float* __restrict__ sxr,
    const float* __restrict__ swbuf,
    float* __restrict__ C)
{
  __shared__ signed char sA[2][BM * BKB];   // 64 KiB
  __shared__ signed char sB[2][BN * BKB];   // 64 KiB

  constexpr int NBM = MDIM / BM;   // 32
  constexpr int NBN = NDIM / BN;   // 16
  constexpr int NWG = NBM * NBN;   // 512
  int bid = (int)blockIdx.x;
  int swz = (bid & 7) * (NWG >> 3) + (bid >> 3);
  int bm = swz / NBN, bn = swz % NBN;
  int m0 = bm * BM, n0 = bn * BN;

  int t = (int)threadIdx.x;
  int lane = t & 63, wid = t >> 6;
  int wm = wid >> 2, wn = wid & 3;     // 2 (M) x 4 (N) waves; 128x64 per wave
  int lr = lane & 15, lk = lane >> 4;

  // staging: dest linear t*16B, source slot pre-swizzled (involution p^(row&7))
  int scol = (((t & 7) ^ ((t >> 3) & 7)) << 4);   // bytes
  const signed char* gA = A + (size_t)(m0 + (t >> 3)) * KDIM + scol;
  const signed char* gB = Bw + (size_t)(n0 + (t >> 3)) * KDIM + scol;

#define STG_A(c, kt, R0) gld_lds16(gA + (size_t)(R0) * KDIM + (kt) * BKB, &sA[c][(R0) * BKB + t * 16])
#define STG_B(c, kt, R0) gld_lds16(gB + (size_t)(R0) * KDIM + (kt) * BKB, &sB[c][(R0) * BKB + t * 16])

  // ds_read fragment addressing (swizzled, bytes) — R7-proven geometry
  int aswz = (lr & 7) << 4;
  int c0 = (lk * 16) ^ aswz;        // kstep 0: k-bytes 0..63
  int c1 = (64 + lk * 16) ^ aswz;   // kstep 1: k-bytes 64..127

  i32x4 avA[4][2], avB[4][2];   // msub-0 / msub-1 fragment sets (separate: WAR-free)
  i32x4 bvA[2][2], bvB[2][2];   // nsub-0 / nsub-1
  i32x4 acc[8][4];
#pragma unroll
  for (int i = 0; i < 8; ++i)
#pragma unroll
    for (int j = 0; j < 4; ++j) acc[i][j] = (i32x4){0, 0, 0, 0};

#define LDA_GRP(c, msub, AV) do { \
  _Pragma("unroll") \
  for (int mi = 0; mi < 4; ++mi) { \
    const signed char* p_ = &sA[c][(wm * 128 + (msub) * 64 + mi * 16 + lr) * BKB]; \
    AV[mi][0] = *(const i32x4*)(p_ + c0); \
    AV[mi][1] = *(const i32x4*)(p_ + c1); \
  } } while (0)

#define LDB_GRP(c, nsub, BV) do { \
  _Pragma("unroll") \
  for (int ni = 0; ni < 2; ++ni) { \
    const signed char* p_ = &sB[c][(wn * 64 + (nsub) * 32 + ni * 16 + lr) * BKB]; \
    BV[ni][0] = *(const i32x4*)(p_ + c0); \
    BV[ni][1] = *(const i32x4*)(p_ + c1); \
  } } while (0)

#define MMA_Q(msub, nsub, AV, BV) do { \
  __builtin_amdgcn_s_setprio(1); \
  _Pragma("unroll") \
  for (int mi = 0; mi < 4; ++mi) \
    _Pragma("unroll") \
    for (int ni = 0; ni < 2; ++ni) { \
      acc[(msub) * 4 + mi][(nsub) * 2 + ni] = __builtin_amdgcn_mfma_i32_16x16x64_i8( \
          AV[mi][0], BV[ni][0], acc[(msub) * 4 + mi][(nsub) * 2 + ni], 0, 0, 0); \
      acc[(msub) * 4 + mi][(nsub) * 2 + ni] = __builtin_amdgcn_mfma_i32_16x16x64_i8( \
          AV[mi][1], BV[ni][1], acc[(msub) * 4 + mi][(nsub) * 2 + ni], 0, 0, 0); \
    } \
  __builtin_amdgcn_s_setprio(0); \
} while (0)

#define SB0() __builtin_amdgcn_sched_barrier(0)
#define BAR() __builtin_amdgcn_s_barrier()

  // Prologue: stage tile 0 into buf0, drain, barrier; read-ahead Q0 operands.
  STG_B(0, 0, 0); STG_B(0, 0, 64); STG_B(0, 0, 128); STG_B(0, 0, 192);
  STG_A(0, 0, 0); STG_A(0, 0, 64); STG_A(0, 0, 128); STG_A(0, 0, 192);
  asm volatile("s_waitcnt vmcnt(0)" ::: "memory");
  BAR();
  LDA_GRP(0, 0, avA); LDB_GRP(0, 0, bvA);   // 12 reads in flight
  SB0();

  // DS FIFO at waits: P0 lgkm(4): [avA+bvA:12][bvB:4] -> drain Q0 set.
  //                   P1 lgkm(8): [bvB:4][avB:8] -> drain bvB.
  //                   P2 lgkm(0): [avB:8] -> drain avB.
  // All reads of buf c drained by P2; BAR at P3 releases next-tile writes into c.
  // vmcnt(0)@P3 drains this wave's own stages (P0 B's, P1 A's); BAR then
  // guarantees ALL waves' DMA into c^1 complete -> post-BAR read-ahead is race-free.
#define TILE(c, kt) do { \
  const bool st_ = (kt) + 1 < NKT; \
  /* P0: issue bvB + B-stages; mma Q00 */ \
  LDB_GRP(c, 1, bvB); \
  if (st_) { STG_B((c) ^ 1, (kt) + 1, 0); STG_B((c) ^ 1, (kt) + 1, 64); \
             STG_B((c) ^ 1, (kt) + 1, 128); STG_B((c) ^ 1, (kt) + 1, 192); } \
  SB0(); \
  asm volatile("s_waitcnt lgkmcnt(4)" ::: "memory"); SB0(); \
  MMA_Q(0, 0, avA, bvA); \
  /* P1: issue avB + A-stages; mma Q01 */ \
  LDA_GRP(c, 1, avB); \
  if (st_) { STG_A((c) ^ 1, (kt) + 1, 0); STG_A((c) ^ 1, (kt) + 1, 64); \
             STG_A((c) ^ 1, (kt) + 1, 128); STG_A((c) ^ 1, (kt) + 1, 192); } \
  SB0(); \
  asm volatile("s_waitcnt lgkmcnt(8)" ::: "memory"); SB0(); \
  MMA_Q(0, 1, avA, bvB); \
  /* P2: mma Q10 */ \
  asm volatile("s_waitcnt lgkmcnt(0)" ::: "memory"); SB0(); \
  MMA_Q(1, 0, avB, bvA); \
  /* P3: drain own DMA; barrier; read-ahead next tile Q0; mma Q11 */ \
  if (st_) { asm volatile("s_waitcnt vmcnt(0)" ::: "memory"); } \
  BAR(); \
  if (st_) { LDA_GRP((c) ^ 1, 0, avA); LDB_GRP((c) ^ 1, 0, bvA); SB0(); } \
  MMA_Q(1, 1, avB, bvB); \
} while (0)

  for (int kt = 0; kt < NKT; kt += 2) {
    TILE(0, kt);
    TILE(1, kt + 1);
  }

  // Epilogue: C/D col = lane&15, row = (lane>>4)*4 + reg; out = acc*sx[row]*sw + bias
  float sw = swbuf[0];
  float bvv[4];
#pragma unroll
  for (int fn = 0; fn < 4; ++fn) bvv[fn] = bias[n0 + wn * 64 + fn * 16 + lr];
#pragma unroll
  for (int fm = 0; fm < 8; ++fm) {
    int row0 = m0 + wm * 128 + fm * 16 + lk * 4;
    float sx_[4];
#pragma unroll
    for (int r = 0; r < 4; ++r) sx_[r] = sxr[row0 + r] * sw;
#pragma unroll
    for (int fn = 0; fn < 4; ++fn) {
      int col = n0 + wn * 64 + fn * 16 + lr;
#pragma unroll
      for (int r = 0; r < 4; ++r)
        C[(size_t)(row0 + r) * NDIM + col] = (float)acc[fm][fn][r] * sx_[r] + bvv[fn];
    }
  }
#undef TILE
#undef MMA_Q
#undef LDB_GRP
#undef LDA_GRP
#undef STG_A
#undef STG_B
#undef SB0
#undef BAR
}

// ---- exact-f32 fallback (used only if ws too small) ----
__global__ __launch_bounds__(256) void toep_f32_fallback(
    const float* __restrict__ X, const float* __restrict__ P,
    const float* __restrict__ bias, float* __restrict__ C)
{
  constexpr int TM = 64, TN = 64, TK = 32;
  __shared__ float xs[TM][TK + 1];
  __shared__ float win[TN + TK];
  int bm = blockIdx.x / (NDIM / TN);
  int bn = blockIdx.x % (NDIM / TN);
  int m0 = bm * TM, n0 = bn * TN;
  int t = (int)threadIdx.x;
  int tx = t & 15, ty = t >> 4;
  float acc[4][4] = {};
  for (int k0 = 0; k0 < KDIM; k0 += TK) {
    __syncthreads();
    for (int i = t; i < TM * TK; i += 256) {
      int r = i >> 5, c = i & 31;
      xs[r][c] = X[(size_t)(m0 + r) * KDIM + k0 + c];
    }
    if (t < TN + TK - 1) win[t] = P[(NDIM - 1) - n0 - (TN - 1) + k0 + t];
    __syncthreads();
    for (int kk = 0; kk < TK; ++kk) {
      float xv[4];
#pragma unroll
      for (int i = 0; i < 4; ++i) xv[i] = xs[ty * 4 + i][kk];
#pragma unroll
      for (int j = 0; j < 4; ++j) {
        float wv = win[kk + (TN - 1) - (tx * 4 + j)];
#pragma unroll
        for (int i = 0; i < 4; ++i) acc[i][j] += xv[i] * wv;
      }
    }
  }
#pragma unroll
  for (int i = 0; i < 4; ++i)
#pragma unroll
    for (int j = 0; j < 4; ++j)
      C[(size_t)(m0 + ty * 4 + i) * NDIM + n0 + tx * 4 + j] = acc[i][j] + bias[n0 + tx * 4 + j];
}

extern "C" void kernel_launch(void* const* d_in, const int* in_sizes, int n_in,
                              void* d_out, int out_size, void* d_ws, size_t ws_size,
                              hipStream_t stream) {
  const float* x = (const float*)d_in[0];
  const float* params = (const float*)d_in[1];
  const float* bias = (const float*)d_in[2];
  float* out = (float*)d_out;

  const size_t xq_off = 0;
  const size_t wq_off = (size_t)MDIM * KDIM;
  const size_t sx_off = wq_off + (size_t)NDIM * KDIM;
  const size_t sw_off = sx_off + (size_t)MDIM * 4;
  const size_t need = sw_off + 64;

  if (ws_size >= need) {
    signed char* xq = (signed char*)d_ws + xq_off;
    signed char* wq = (signed char*)d_ws + wq_off;
    float* sxr = (float*)((char*)d_ws + sx_off);
    float* swbuf = (float*)((char*)d_ws + sw_off);
    wscale_kernel<<<1, 256, 0, stream>>>(params, swbuf);
    quant_x_kernel<<<MDIM, 256, 0, stream>>>(x, xq, sxr);
    build_wq_kernel<<<NDIM * KDIM / 16 / 256, 256, 0, stream>>>(params, swbuf, wq);
    toep_gemm_i8<<<(MDIM / BM) * (NDIM / BN), 512, 0, stream>>>(xq, wq, bias, sxr, swbuf, out);
  } else {
    toep_f32_fallback<<<(MDIM / 64) * (NDIM / 64), 256, 0, stream>>>(x, params, bias, out);
  }
}